// Round 12
// baseline (296.217 us; speedup 1.0000x reference)
//
#include <hip/hip_runtime.h>

// HBMA fused: full-search block matching (16x16 blocks, +/-4 search) + predicted
// frame gather. N=8, C=3, H=W=1024.
//
// R12 = R8 (best, 230us, absmax 0) + LDS double-buffered prefetch over 4
// vertically-adjacent strips per wg (2048 wgs). Per iteration: issue next
// strip's global_load_lds into the other buffer (order pinned by
// sched_barrier), compute current strip (byte-identical R8 math), then
// s_waitcnt vmcnt(12) lgkmcnt(0) + raw s_barrier. vmcnt(12): the 12 newest
// vmem ops are this lane's 12 gather stores; all stage loads are older, so
// they are guaranteed complete without ever waiting on store acks. This
// removes the staged-load HBM latency from the per-strip critical path
// (R8 paid it once per 5us workgroup via __syncthreads' vmcnt(0) drain).
// Compute per wave (unchanged): lane = col(16) x dx-group(4), groups 0..2 own
// dx triplets (acc[9][3]=27 regs), 16-lane shfl col-reduce, publish to LDS
// cost array (same-wave, lgkmcnt(0)), in-wave 81-way argmin (ascending-index
// tie-break = jax scan strict <), gather from LDS strip (zero-padded).
// launch_bounds(256,2): empirical VGPR cap 256 ((256,4)->64 spills,
// (512,2)->128 spills). OOB ref chunks load a zeroed 16B block (MV region of
// d_out, zeroed by init_kernel each launch).

namespace {
constexpr int BLKi  = 16;
constexpr int NSDi  = 4;
constexpr int ND    = 9;
constexpr int NDISP = 81;
constexpr int Nn    = 8;
constexpr int Cc    = 3;
constexpr int Hh    = 1024;
constexpr int Ww    = 1024;
constexpr int BHn   = 64;
constexpr int STRIPW = 64;                    // 4 blocks per wg, side by side
constexpr int SW    = 72;                     // strip width  (64 + 8)
constexpr int SH    = 24;                     // strip height (16 + 8)
constexpr int STRIP_FLOATS = Cc * SH * SW;    // 5184
constexpr int STRIP_CHUNKS = STRIP_FLOATS/4;  // 1296 (18/row: chunks never straddle)
constexpr int TGT_FLOATS   = Cc * BLKi * STRIPW; // 3072
constexpr int TOT_CHUNKS   = STRIP_CHUNKS + TGT_FLOATS / 4; // 2064
constexpr int ITERS        = 9;               // ceil(2064/256)
constexpr int LDSF         = ITERS * 256 * 4; // 9216 floats per buffer
constexpr int MV_SIZE = Nn * 2 * BHn * BHn;   // 65536
constexpr int SPW     = 4;                    // strips per wg (vertical)
constexpr int NWG     = Nn * (BHn / SPW) * (Ww / STRIPW); // 2048
}

typedef const __attribute__((address_space(1))) void* gas_ptr;
typedef __attribute__((address_space(3))) void*       las_ptr;

__global__ void init_kernel(float* __restrict__ out) {
    int i = blockIdx.x * 256 + threadIdx.x;
    if (i < MV_SIZE) out[i] = 0.0f;   // MV output = zeros; doubles as zero-source
}

__device__ __forceinline__ void stage_strip(
        float* __restrict__ buf, const float* __restrict__ refn,
        const float* __restrict__ tgtn, const float* __restrict__ zsrc,
        int Y0, int X0, int tid) {
    #pragma unroll
    for (int i = 0; i < ITERS; ++i) {
        const int ck = i * 256 + tid;          // chunk id
        if (ck < TOT_CHUNKS) {
            const float* src;
            if (ck < STRIP_CHUNKS) {
                const int c    = ck / (SH * SW / 4);           // /432
                const int rm   = ck - c * (SH * SW / 4);
                const int r    = rm / (SW / 4);                // /18
                const int colc = (rm - r * (SW / 4)) * 4;
                const int gy   = Y0 - NSDi + r;
                const int gx   = X0 - NSDi + colc;             // 4-aligned
                const bool ok  = ((unsigned)gy < (unsigned)Hh) &&
                                 ((unsigned)gx < (unsigned)Ww);
                src = ok ? (refn + (c << 20) + (gy << 10) + gx) : zsrc;
            } else {
                const int tk   = ck - STRIP_CHUNKS;
                const int c    = tk >> 8;                      // 256 chunks/ch
                const int rm2  = tk & 255;
                const int y    = rm2 >> 4;
                const int colc = (rm2 & 15) * 4;
                src = tgtn + (c << 20) + ((Y0 + y) << 10) + X0 + colc;
            }
            // LDS dest: wave-uniform base; HW adds lane*16B
            __builtin_amdgcn_global_load_lds((gas_ptr)src,
                    (las_ptr)(buf + i * 1024 + (tid & 192) * 4), 16, 0, 0);
        }
    }
    __builtin_amdgcn_sched_barrier(0);  // pin stage loads before later vmem ops
}

__device__ __forceinline__ void compute_strip(
        const float* __restrict__ buf, float* __restrict__ predn,
        float (*costL)[NDISP], int Y0, int X0,
        int wid, int col, int g, int d0, int colS) {
    const float* __restrict__ ldsT = buf + STRIP_FLOATS;

    float acc[ND][3];
    #pragma unroll
    for (int j = 0; j < ND; ++j) {
        acc[j][0] = 0.0f; acc[j][1] = 0.0f; acc[j][2] = 0.0f;
    }

    #pragma unroll 1
    for (int c = 0; c < Cc; ++c) {
        float T[BLKi];
        #pragma unroll
        for (int y = 0; y < BLKi; ++y)
            T[y] = ldsT[(c * BLKi + y) * STRIPW + colS];

        #pragma unroll
        for (int r = 0; r < SH; ++r) {
            const float* rp = buf + (c * SH + r) * SW + colS + d0;
            const float rv0 = rp[0], rv1 = rp[1], rv2 = rp[2];
            #pragma unroll
            for (int j = 0; j < ND; ++j) {
                const int y = r - j;           // compile-time after unroll
                if (y >= 0 && y < BLKi) {
                    const float tv = T[y];
                    acc[j][0] += fabsf(rv0 - tv);
                    acc[j][1] += fabsf(rv1 - tv);
                    acc[j][2] += fabsf(rv2 - tv);
                }
            }
        }
    }

    // ---- reduce over the 16 columns (within each dx-group) ----
    #pragma unroll
    for (int m = 1; m <= 8; m <<= 1)
        #pragma unroll
        for (int j = 0; j < ND; ++j) {
            acc[j][0] += __shfl_xor(acc[j][0], m, 64);
            acc[j][1] += __shfl_xor(acc[j][1], m, 64);
            acc[j][2] += __shfl_xor(acc[j][2], m, 64);
        }

    // ---- publish: lane (g<3, col==jj) writes cost[jj*9 + 3g + dd] ----
    #pragma unroll
    for (int jj = 0; jj < ND; ++jj) {
        if (g < 3 && col == jj) {
            costL[wid][jj * ND + d0 + 0] = acc[jj][0];
            costL[wid][jj * ND + d0 + 1] = acc[jj][1];
            costL[wid][jj * ND + d0 + 2] = acc[jj][2];
        }
    }
    asm volatile("s_waitcnt lgkmcnt(0)" ::: "memory");  // same-wave visibility

    // ---- in-wave argmin over 81, ascending index wins ties ----
    const int lane = (g << 4) + col;
    float bc = costL[wid][lane];
    int   bj = lane;
    if (lane < NDISP - 64) {
        float c2 = costL[wid][lane + 64];
        if (c2 < bc) { bc = c2; bj = lane + 64; }
    }
    #pragma unroll
    for (int m = 1; m <= 32; m <<= 1) {
        float oc = __shfl_xor(bc, m, 64);
        int   oi = __shfl_xor(bj, m, 64);
        if (oc < bc || (oc == bc && oi < bj)) { bc = oc; bj = oi; }
    }
    const int by = bj / ND;                    // dy + 4
    const int bx = bj % ND;                    // dx + 4

    // ---- gather predicted block from LDS strip (already zero-padded) ----
    #pragma unroll 1
    for (int c = 0; c < Cc; ++c) {
        #pragma unroll
        for (int yy = 0; yy < 4; ++yy) {
            const int y = (g << 2) + yy;
            const float v = buf[(c * SH + y + by) * SW + colS + bx];
            predn[(c << 20) + ((Y0 + y) << 10) + X0 + colS] = v;
        }
    }
}

__global__ __launch_bounds__(256, 2) void hbma_kernel(
        const float* __restrict__ ref,
        const float* __restrict__ tgt,
        float* __restrict__ pred,
        const float* __restrict__ zsrc) {
    __shared__ float ldsA[2 * LDSF];           // two strip buffers
    __shared__ float costL[4][NDISP];

    const int tid  = (int)threadIdx.x;
    const int wid  = tid >> 6;                 // wave = which of 4 blocks
    const int lane = tid & 63;
    const int wg   = (int)blockIdx.x;          // 0..2047
    const int n    = wg >> 8;                  // 256 wg per image
    const int rem  = wg & 255;
    const int ygrp = rem >> 4;                 // 0..15 (4 block-rows each)
    const int X0   = (rem & 15) * STRIPW;      // strip origin
    const float* refn  = ref  + (size_t)n * Cc * Hh * Ww;
    const float* tgtn  = tgt  + (size_t)n * Cc * Hh * Ww;
    float*       predn = pred + (size_t)n * Cc * Hh * Ww;

    const int col  = lane & 15;
    const int g    = lane >> 4;
    const int d0   = g * 3;                    // 0,3,6 (9 = idle group, harmless)
    const int colS = (wid << 4) + col;         // column within strip

    float* bufA = ldsA;
    float* bufB = ldsA + LDSF;
    const int Ybase = ygrp * (SPW * BLKi);     // + it*16

    // ---- prologue: stage strip 0 into A ----
    stage_strip(bufA, refn, tgtn, zsrc, Ybase, X0, tid);
    asm volatile("s_waitcnt vmcnt(0)" ::: "memory");
    __builtin_amdgcn_s_barrier();
    __builtin_amdgcn_sched_barrier(0);

    #pragma unroll 1
    for (int base = 0; base < SPW; base += 2) {
        // ---- even strip: compute A, prefetch (base+1) into B ----
        if (base + 1 < SPW)
            stage_strip(bufB, refn, tgtn, zsrc, Ybase + (base + 1) * BLKi, X0, tid);
        compute_strip(bufA, predn, costL, Ybase + base * BLKi, X0,
                      wid, col, g, d0, colS);
        asm volatile("s_waitcnt vmcnt(12) lgkmcnt(0)" ::: "memory");
        __builtin_amdgcn_s_barrier();
        __builtin_amdgcn_sched_barrier(0);

        // ---- odd strip: compute B, prefetch (base+2) into A ----
        if (base + 2 < SPW)
            stage_strip(bufA, refn, tgtn, zsrc, Ybase + (base + 2) * BLKi, X0, tid);
        compute_strip(bufB, predn, costL, Ybase + (base + 1) * BLKi, X0,
                      wid, col, g, d0, colS);
        asm volatile("s_waitcnt vmcnt(12) lgkmcnt(0)" ::: "memory");
        __builtin_amdgcn_s_barrier();
        __builtin_amdgcn_sched_barrier(0);
    }
}

extern "C" void kernel_launch(void* const* d_in, const int* in_sizes, int n_in,
                              void* d_out, int out_size, void* d_ws, size_t ws_size,
                              hipStream_t stream) {
    const float* ref = (const float*)d_in[0];
    const float* tgt = (const float*)d_in[1];
    float* out = (float*)d_out;

    init_kernel<<<dim3((MV_SIZE + 255) / 256), dim3(256), 0, stream>>>(out);

    // zsrc = MV region (zeroed by init_kernel on this stream, never written after)
    hbma_kernel<<<dim3(NWG), dim3(256), 0, stream>>>(ref, tgt, out + MV_SIZE, out);
}